// Round 1
// baseline (304.672 us; speedup 1.0000x reference)
//
#include <hip/hip_runtime.h>

#define B_LEN 32
#define C_LEN 512
#define L_LEN 4096
#define H_LEN 8
#define WIN 9
#define PADW 4

// ---------------- Kernel 1: conv partial over a C-split ----------------
// grid (L/1024, B, nsplit), block 256. Thread t owns l = l0 + 4t .. 4t+3.
// Stages x[c-chunk][1032] in LDS (1024 + 8 halo), W read via wave-uniform
// scalar loads (SGPR operand in FMA).
#define K1_LT 1024
#define K1_CC 16
#define K1_ST 1032 // LDS row stride in floats (1024 + 8 halo)

__global__ __launch_bounds__(256, 2) void conv_partial(
    const float* __restrict__ x, const float* __restrict__ W,
    float* __restrict__ part, int cper)
{
  __shared__ float xs[K1_CC * K1_ST];
  const int t = threadIdx.x;
  const int l0 = blockIdx.x * K1_LT;
  const int b = blockIdx.y;
  const int cbase = blockIdx.z * cper;

  float acc[H_LEN][4];
#pragma unroll
  for (int h = 0; h < H_LEN; ++h)
#pragma unroll
    for (int j = 0; j < 4; ++j) acc[h][j] = 0.f;

  const float* xb = x + (size_t)b * C_LEN * L_LEN;
  const int nchunk = cper / K1_CC;

  for (int chunk = 0; chunk < nchunk; ++chunk) {
    const int c0 = cbase + chunk * K1_CC;
    __syncthreads();
    // stage x[c0 .. c0+16) x [l0-4, l0+1028) with zero padding
    for (int i = t; i < K1_CC * (K1_ST / 4); i += 256) {
      const int c = i / (K1_ST / 4);
      const int p4 = i - c * (K1_ST / 4);
      const int g = l0 - PADW + 4 * p4; // multiple of 4 -> whole float4 in/out
      float4 v = make_float4(0.f, 0.f, 0.f, 0.f);
      if (g >= 0 && g < L_LEN)
        v = *reinterpret_cast<const float4*>(&xb[(size_t)(c0 + c) * L_LEN + g]);
      *reinterpret_cast<float4*>(&xs[c * K1_ST + 4 * p4]) = v;
    }
    __syncthreads();
    for (int c = 0; c < K1_CC; ++c) {
      float xv[12];
      const float4 a0 = *reinterpret_cast<const float4*>(&xs[c * K1_ST + 4 * t]);
      const float4 a1 = *reinterpret_cast<const float4*>(&xs[c * K1_ST + 4 * t + 4]);
      const float4 a2 = *reinterpret_cast<const float4*>(&xs[c * K1_ST + 4 * t + 8]);
      xv[0] = a0.x; xv[1] = a0.y; xv[2]  = a0.z; xv[3]  = a0.w;
      xv[4] = a1.x; xv[5] = a1.y; xv[6]  = a1.z; xv[7]  = a1.w;
      xv[8] = a2.x; xv[9] = a2.y; xv[10] = a2.z; xv[11] = a2.w;
      const float* Wc = W + (size_t)(c0 + c) * WIN; // wave-uniform address
#pragma unroll
      for (int h = 0; h < H_LEN; ++h) {
        const float* Wh = Wc + (size_t)h * (C_LEN * WIN);
#pragma unroll
        for (int w = 0; w < WIN; ++w) {
          const float wv = Wh[w]; // uniform -> SGPR
#pragma unroll
          for (int j = 0; j < 4; ++j)
            acc[h][j] = fmaf(xv[w + j], wv, acc[h][j]);
        }
      }
    }
  }
  float* dst = part + ((size_t)blockIdx.z * B_LEN * H_LEN + (size_t)b * H_LEN) * L_LEN
             + l0 + 4 * t;
#pragma unroll
  for (int h = 0; h < H_LEN; ++h) {
    float4 v;
    v.x = acc[h][0]; v.y = acc[h][1]; v.z = acc[h][2]; v.w = acc[h][3];
    *reinterpret_cast<float4*>(dst + (size_t)h * L_LEN) = v;
  }
}

// ---------------- Kernel 2: sum partials + softmax over L ----------------
// grid (B*H), block 256; each thread owns 16 elements of the 4096 row.
__global__ __launch_bounds__(256) void softmax_rows(
    const float* __restrict__ part, float* __restrict__ focus, int nsplit)
{
  __shared__ float red[256];
  const int r = blockIdx.x; // b*H + h
  const int t = threadIdx.x;
  const size_t PART = (size_t)B_LEN * H_LEN * L_LEN;
  float v[16];
#pragma unroll
  for (int k = 0; k < 4; ++k) {
    const int i4 = (t + 256 * k) * 4;
    float4 a = *reinterpret_cast<const float4*>(&part[(size_t)r * L_LEN + i4]);
    v[4 * k + 0] = a.x; v[4 * k + 1] = a.y; v[4 * k + 2] = a.z; v[4 * k + 3] = a.w;
  }
  for (int s = 1; s < nsplit; ++s) {
#pragma unroll
    for (int k = 0; k < 4; ++k) {
      const int i4 = (t + 256 * k) * 4;
      float4 a = *reinterpret_cast<const float4*>(&part[(size_t)s * PART + (size_t)r * L_LEN + i4]);
      v[4 * k + 0] += a.x; v[4 * k + 1] += a.y; v[4 * k + 2] += a.z; v[4 * k + 3] += a.w;
    }
  }
  // note: bias b[h] is constant along L -> softmax-invariant -> skipped
  float m = v[0];
#pragma unroll
  for (int k = 1; k < 16; ++k) m = fmaxf(m, v[k]);
  red[t] = m;
  __syncthreads();
  for (int s = 128; s > 0; s >>= 1) {
    if (t < s) red[t] = fmaxf(red[t], red[t + s]);
    __syncthreads();
  }
  m = red[0];
  __syncthreads();
  float sum = 0.f;
#pragma unroll
  for (int k = 0; k < 16; ++k) { v[k] = __expf(v[k] - m); sum += v[k]; }
  red[t] = sum;
  __syncthreads();
  for (int s = 128; s > 0; s >>= 1) {
    if (t < s) red[t] += red[t + s];
    __syncthreads();
  }
  const float inv = 1.f / red[0];
#pragma unroll
  for (int k = 0; k < 4; ++k) {
    const int i4 = (t + 256 * k) * 4;
    float4 a;
    a.x = v[4 * k + 0] * inv; a.y = v[4 * k + 1] * inv;
    a.z = v[4 * k + 2] * inv; a.w = v[4 * k + 3] * inv;
    *reinterpret_cast<float4*>(&focus[(size_t)r * L_LEN + i4]) = a;
  }
}

// ---------------- Kernel 3: pooled = sum_l focus*x, then max over h ----------------
// grid (C/64, B), block 256. LDS-transposed x tile [64c][68] (odd stride ->
// conflict-free b128 column reads); focus via wave-uniform scalar loads.
#define K3_ST 68

__global__ __launch_bounds__(256) void pool_max(
    const float* __restrict__ x, const float* __restrict__ focus,
    float* __restrict__ out)
{
  __shared__ float xs[64 * K3_ST];
  __shared__ float pool[4][64][2];
  const int t = threadIdx.x;
  const int cl = t & 63;
  const int p = t >> 6;                              // h-pair group 0..3 (wave-uniform)
  const int pu = __builtin_amdgcn_readfirstlane(p);  // force SGPR for focus addressing
  const int b = blockIdx.y;
  const int c0 = blockIdx.x * 64;
  const float* f0 = focus + ((size_t)b * H_LEN + pu) * L_LEN;
  const float* f1 = f0 + 4 * (size_t)L_LEN;
  const float* xb = x + (size_t)b * C_LEN * L_LEN;
  const int srow = t >> 4;
  const int scol = (t & 15) * 4;
  float acc0 = 0.f, acc1 = 0.f;

  for (int l0 = 0; l0 < L_LEN; l0 += 64) {
    __syncthreads();
#pragma unroll
    for (int pass = 0; pass < 4; ++pass) {
      const int c = srow + pass * 16;
      float4 v = *reinterpret_cast<const float4*>(&xb[(size_t)(c0 + c) * L_LEN + l0 + scol]);
      *reinterpret_cast<float4*>(&xs[c * K3_ST + scol]) = v;
    }
    __syncthreads();
#pragma unroll
    for (int l4 = 0; l4 < 16; ++l4) {
      const float4 xv = *reinterpret_cast<const float4*>(&xs[cl * K3_ST + 4 * l4]);
      const int li = l0 + 4 * l4;
      acc0 = fmaf(xv.x, f0[li + 0], acc0);
      acc0 = fmaf(xv.y, f0[li + 1], acc0);
      acc0 = fmaf(xv.z, f0[li + 2], acc0);
      acc0 = fmaf(xv.w, f0[li + 3], acc0);
      acc1 = fmaf(xv.x, f1[li + 0], acc1);
      acc1 = fmaf(xv.y, f1[li + 1], acc1);
      acc1 = fmaf(xv.z, f1[li + 2], acc1);
      acc1 = fmaf(xv.w, f1[li + 3], acc1);
    }
  }
  pool[p][cl][0] = acc0;
  pool[p][cl][1] = acc1;
  __syncthreads();
  if (t < 64) {
    float m = pool[0][t][0];
#pragma unroll
    for (int q = 0; q < 4; ++q) {
      m = fmaxf(m, pool[q][t][0]);
      m = fmaxf(m, pool[q][t][1]);
    }
    out[(size_t)b * C_LEN + c0 + t] = m;
  }
}

extern "C" void kernel_launch(void* const* d_in, const int* in_sizes, int n_in,
                              void* d_out, int out_size, void* d_ws, size_t ws_size,
                              hipStream_t stream)
{
  const float* x = (const float*)d_in[0];
  const float* W = (const float*)d_in[1];
  // d_in[2] = bias: constant along L, softmax-invariant -> no effect on output.
  float* out = (float*)d_out;
  float* ws = (float*)d_ws;

  const size_t PART = (size_t)B_LEN * H_LEN * L_LEN; // 1M floats = 4 MB
  int nsplit = 4;
  if (ws_size < (size_t)(4 + 1) * PART * sizeof(float)) nsplit = 2;
  if (ws_size < (size_t)(2 + 1) * PART * sizeof(float)) nsplit = 1;

  float* part = ws;
  float* focus = ws + (size_t)nsplit * PART;
  const int cper = C_LEN / nsplit;

  hipLaunchKernelGGL(conv_partial, dim3(L_LEN / K1_LT, B_LEN, nsplit), dim3(256), 0,
                     stream, x, W, part, cper);
  hipLaunchKernelGGL(softmax_rows, dim3(B_LEN * H_LEN), dim3(256), 0,
                     stream, part, focus, nsplit);
  hipLaunchKernelGGL(pool_max, dim3(C_LEN / 64, B_LEN), dim3(256), 0,
                     stream, x, focus, out);
}

// Round 2
// 275.764 us; speedup vs baseline: 1.1048x; 1.1048x over previous
//
#include <hip/hip_runtime.h>

#define B_LEN 32
#define C_LEN 512
#define L_LEN 4096
#define H_LEN 8
#define WIN 9
#define PADW 4

// ---------------- Kernel 1: conv partial over a C-split ----------------
// grid (L/1024, B, nsplit), block 256. Thread t owns l = l0 + 4t .. 4t+3.
// Stages x[c-chunk][1032] in LDS (1024 + 8 halo), W read via wave-uniform
// scalar loads (SGPR operand in FMA).
// K1_CC=8 -> 33KB LDS -> 4 blocks/CU (16 waves/CU) for latency hiding.
#define K1_LT 1024
#define K1_CC 8
#define K1_ST 1032 // LDS row stride in floats (1024 + 8 halo)

__global__ __launch_bounds__(256, 4) void conv_partial(
    const float* __restrict__ x, const float* __restrict__ W,
    float* __restrict__ part, int cper)
{
  __shared__ float xs[K1_CC * K1_ST];
  const int t = threadIdx.x;
  const int l0 = blockIdx.x * K1_LT;
  const int b = blockIdx.y;
  const int cbase = blockIdx.z * cper;

  float acc[H_LEN][4];
#pragma unroll
  for (int h = 0; h < H_LEN; ++h)
#pragma unroll
    for (int j = 0; j < 4; ++j) acc[h][j] = 0.f;

  const float* xb = x + (size_t)b * C_LEN * L_LEN;
  const int nchunk = cper / K1_CC;

  for (int chunk = 0; chunk < nchunk; ++chunk) {
    const int c0 = cbase + chunk * K1_CC;
    __syncthreads();
    // stage x[c0 .. c0+8) x [l0-4, l0+1028) with zero padding
    for (int i = t; i < K1_CC * (K1_ST / 4); i += 256) {
      const int c = i / (K1_ST / 4);
      const int p4 = i - c * (K1_ST / 4);
      const int g = l0 - PADW + 4 * p4; // multiple of 4 -> whole float4 in/out
      float4 v = make_float4(0.f, 0.f, 0.f, 0.f);
      if (g >= 0 && g < L_LEN)
        v = *reinterpret_cast<const float4*>(&xb[(size_t)(c0 + c) * L_LEN + g]);
      *reinterpret_cast<float4*>(&xs[c * K1_ST + 4 * p4]) = v;
    }
    __syncthreads();
#pragma unroll
    for (int c = 0; c < K1_CC; ++c) {
      float xv[12];
      const float4 a0 = *reinterpret_cast<const float4*>(&xs[c * K1_ST + 4 * t]);
      const float4 a1 = *reinterpret_cast<const float4*>(&xs[c * K1_ST + 4 * t + 4]);
      const float4 a2 = *reinterpret_cast<const float4*>(&xs[c * K1_ST + 4 * t + 8]);
      xv[0] = a0.x; xv[1] = a0.y; xv[2]  = a0.z; xv[3]  = a0.w;
      xv[4] = a1.x; xv[5] = a1.y; xv[6]  = a1.z; xv[7]  = a1.w;
      xv[8] = a2.x; xv[9] = a2.y; xv[10] = a2.z; xv[11] = a2.w;
      const float* Wc = W + (size_t)(c0 + c) * WIN; // wave-uniform address
#pragma unroll
      for (int h = 0; h < H_LEN; ++h) {
        const float* Wh = Wc + (size_t)h * (C_LEN * WIN);
#pragma unroll
        for (int w = 0; w < WIN; ++w) {
          const float wv = Wh[w]; // uniform -> SGPR
#pragma unroll
          for (int j = 0; j < 4; ++j)
            acc[h][j] = fmaf(xv[w + j], wv, acc[h][j]);
        }
      }
    }
  }
  float* dst = part + ((size_t)blockIdx.z * B_LEN * H_LEN + (size_t)b * H_LEN) * L_LEN
             + l0 + 4 * t;
#pragma unroll
  for (int h = 0; h < H_LEN; ++h) {
    float4 v;
    v.x = acc[h][0]; v.y = acc[h][1]; v.z = acc[h][2]; v.w = acc[h][3];
    *reinterpret_cast<float4*>(dst + (size_t)h * L_LEN) = v;
  }
}

// ---------------- Kernel 2: sum partials + softmax over L ----------------
// grid (B*H), block 256; each thread owns 16 elements of the 4096 row.
__global__ __launch_bounds__(256) void softmax_rows(
    const float* __restrict__ part, float* __restrict__ focus, int nsplit)
{
  __shared__ float red[256];
  const int r = blockIdx.x; // b*H + h
  const int t = threadIdx.x;
  const size_t PART = (size_t)B_LEN * H_LEN * L_LEN;
  float v[16];
#pragma unroll
  for (int k = 0; k < 4; ++k) {
    const int i4 = (t + 256 * k) * 4;
    float4 a = *reinterpret_cast<const float4*>(&part[(size_t)r * L_LEN + i4]);
    v[4 * k + 0] = a.x; v[4 * k + 1] = a.y; v[4 * k + 2] = a.z; v[4 * k + 3] = a.w;
  }
  for (int s = 1; s < nsplit; ++s) {
#pragma unroll
    for (int k = 0; k < 4; ++k) {
      const int i4 = (t + 256 * k) * 4;
      float4 a = *reinterpret_cast<const float4*>(&part[(size_t)s * PART + (size_t)r * L_LEN + i4]);
      v[4 * k + 0] += a.x; v[4 * k + 1] += a.y; v[4 * k + 2] += a.z; v[4 * k + 3] += a.w;
    }
  }
  // note: bias b[h] is constant along L -> softmax-invariant -> skipped
  float m = v[0];
#pragma unroll
  for (int k = 1; k < 16; ++k) m = fmaxf(m, v[k]);
  red[t] = m;
  __syncthreads();
  for (int s = 128; s > 0; s >>= 1) {
    if (t < s) red[t] = fmaxf(red[t], red[t + s]);
    __syncthreads();
  }
  m = red[0];
  __syncthreads();
  float sum = 0.f;
#pragma unroll
  for (int k = 0; k < 16; ++k) { v[k] = __expf(v[k] - m); sum += v[k]; }
  red[t] = sum;
  __syncthreads();
  for (int s = 128; s > 0; s >>= 1) {
    if (t < s) red[t] += red[t + s];
    __syncthreads();
  }
  const float inv = 1.f / red[0];
#pragma unroll
  for (int k = 0; k < 4; ++k) {
    const int i4 = (t + 256 * k) * 4;
    float4 a;
    a.x = v[4 * k + 0] * inv; a.y = v[4 * k + 1] * inv;
    a.z = v[4 * k + 2] * inv; a.w = v[4 * k + 3] * inv;
    *reinterpret_cast<float4*>(&focus[(size_t)r * L_LEN + i4]) = a;
  }
}

// ---------------- Kernel 3: pooled = sum_l focus*x, then max over h ----------------
// grid (C/64, B), block 256. LDS-transposed x tile [64c][68] (odd stride ->
// conflict-free b128 column reads); focus via wave-uniform scalar loads.
#define K3_ST 68

__global__ __launch_bounds__(256) void pool_max(
    const float* __restrict__ x, const float* __restrict__ focus,
    float* __restrict__ out)
{
  __shared__ float xs[64 * K3_ST];
  __shared__ float pool[4][64][2];
  const int t = threadIdx.x;
  const int cl = t & 63;
  const int p = t >> 6;                              // h-pair group 0..3 (wave-uniform)
  const int pu = __builtin_amdgcn_readfirstlane(p);  // force SGPR for focus addressing
  const int b = blockIdx.y;
  const int c0 = blockIdx.x * 64;
  const float* f0 = focus + ((size_t)b * H_LEN + pu) * L_LEN;
  const float* f1 = f0 + 4 * (size_t)L_LEN;
  const float* xb = x + (size_t)b * C_LEN * L_LEN;
  const int srow = t >> 4;
  const int scol = (t & 15) * 4;
  float acc0 = 0.f, acc1 = 0.f;

  for (int l0 = 0; l0 < L_LEN; l0 += 64) {
    __syncthreads();
#pragma unroll
    for (int pass = 0; pass < 4; ++pass) {
      const int c = srow + pass * 16;
      float4 v = *reinterpret_cast<const float4*>(&xb[(size_t)(c0 + c) * L_LEN + l0 + scol]);
      *reinterpret_cast<float4*>(&xs[c * K3_ST + scol]) = v;
    }
    __syncthreads();
#pragma unroll
    for (int l4 = 0; l4 < 16; ++l4) {
      const float4 xv = *reinterpret_cast<const float4*>(&xs[cl * K3_ST + 4 * l4]);
      const int li = l0 + 4 * l4;
      acc0 = fmaf(xv.x, f0[li + 0], acc0);
      acc0 = fmaf(xv.y, f0[li + 1], acc0);
      acc0 = fmaf(xv.z, f0[li + 2], acc0);
      acc0 = fmaf(xv.w, f0[li + 3], acc0);
      acc1 = fmaf(xv.x, f1[li + 0], acc1);
      acc1 = fmaf(xv.y, f1[li + 1], acc1);
      acc1 = fmaf(xv.z, f1[li + 2], acc1);
      acc1 = fmaf(xv.w, f1[li + 3], acc1);
    }
  }
  pool[p][cl][0] = acc0;
  pool[p][cl][1] = acc1;
  __syncthreads();
  if (t < 64) {
    float m = pool[0][t][0];
#pragma unroll
    for (int q = 0; q < 4; ++q) {
      m = fmaxf(m, pool[q][t][0]);
      m = fmaxf(m, pool[q][t][1]);
    }
    out[(size_t)b * C_LEN + c0 + t] = m;
  }
}

extern "C" void kernel_launch(void* const* d_in, const int* in_sizes, int n_in,
                              void* d_out, int out_size, void* d_ws, size_t ws_size,
                              hipStream_t stream)
{
  const float* x = (const float*)d_in[0];
  const float* W = (const float*)d_in[1];
  // d_in[2] = bias: constant along L, softmax-invariant -> no effect on output.
  float* out = (float*)d_out;
  float* ws = (float*)d_ws;

  const size_t PART = (size_t)B_LEN * H_LEN * L_LEN; // 1M floats = 4 MB
  int nsplit = 8;
  if (ws_size < (size_t)(8 + 1) * PART * sizeof(float)) nsplit = 4;
  if (ws_size < (size_t)(4 + 1) * PART * sizeof(float)) nsplit = 2;
  if (ws_size < (size_t)(2 + 1) * PART * sizeof(float)) nsplit = 1;

  float* part = ws;
  float* focus = ws + (size_t)nsplit * PART;
  const int cper = C_LEN / nsplit;

  hipLaunchKernelGGL(conv_partial, dim3(L_LEN / K1_LT, B_LEN, nsplit), dim3(256), 0,
                     stream, x, W, part, cper);
  hipLaunchKernelGGL(softmax_rows, dim3(B_LEN * H_LEN), dim3(256), 0,
                     stream, part, focus, nsplit);
  hipLaunchKernelGGL(pool_max, dim3(C_LEN / 64, B_LEN), dim3(256), 0,
                     stream, x, focus, out);
}

// Round 3
// 190.696 us; speedup vs baseline: 1.5977x; 1.4461x over previous
//
#include <hip/hip_runtime.h>

#define B_LEN 32
#define C_LEN 512
#define L_LEN 4096
#define H_LEN 8
#define WIN 9
#define PADW 4

// ---------------- Kernel 1: conv partial over a C-split ----------------
// grid (L/1024, B, nsplit), block 256. Thread t owns l = l0 + 4t .. 4t+3.
// Double-buffered async staging: global_load_lds(width16) for chunk k+1 is
// issued BEFORE computing chunk k, so the vmcnt(0) drain at the barrier is
// free (compute ~2300 cyc >> ~900 cyc HBM latency). LDS 2*4*1032*4 = 33 KB
// -> 4 blocks/CU.
#define K1_LT 1024
#define K1_CC 4
#define K1_ST 1032 // row: [0..4) left halo | [4..1028) bulk | [1028..1032) right halo

__device__ inline void gload_lds16(const float* g, float* l) {
  __builtin_amdgcn_global_load_lds(
      (const __attribute__((address_space(1))) void*)g,
      (__attribute__((address_space(3))) void*)l, 16, 0, 0);
}

__global__ __launch_bounds__(256, 4) void conv_partial(
    const float* __restrict__ x, const float* __restrict__ W,
    float* __restrict__ part, int cper)
{
  __shared__ float xs[2][K1_CC][K1_ST];
  const int t = threadIdx.x;
  const int lane = t & 63;
  const int wid = t >> 6; // wave id = staged row
  const int l0 = blockIdx.x * K1_LT;
  const int b = blockIdx.y;
  const int cbase = blockIdx.z * cper;
  const float* xb = x + (size_t)b * C_LEN * L_LEN;
  const int nchunk = cper / K1_CC;

  float acc[H_LEN][4];
#pragma unroll
  for (int h = 0; h < H_LEN; ++h)
#pragma unroll
    for (int j = 0; j < 4; ++j) acc[h][j] = 0.f;

  // stage: wave `wid` loads channel row (cbase + chunk*4 + wid)
  auto STAGE = [&](int buf, int chunk) {
    const int c = cbase + chunk * K1_CC + wid;
    const float* src = xb + (size_t)c * L_LEN + l0;
    float* dstrow = &xs[buf][wid][0];
#pragma unroll
    for (int q = 0; q < 4; ++q)
      gload_lds16(src + q * 256 + lane * 4, dstrow + 4 + q * 256);
    if (lane < 2) {
      const int g = (lane == 0) ? (l0 - PADW) : (l0 + K1_LT);
      float4 v = make_float4(0.f, 0.f, 0.f, 0.f);
      if (g >= 0 && g < L_LEN)
        v = *reinterpret_cast<const float4*>(xb + (size_t)c * L_LEN + g);
      *reinterpret_cast<float4*>(dstrow + ((lane == 0) ? 0 : (K1_LT + 4))) = v;
    }
  };

  STAGE(0, 0);
  __syncthreads(); // compiler emits vmcnt(0) lgkmcnt(0) before s_barrier

  int buf = 0;
  for (int chunk = 0; chunk < nchunk; ++chunk) {
    if (chunk + 1 < nchunk) STAGE(buf ^ 1, chunk + 1); // prefetch, no wait
    const int c0 = cbase + chunk * K1_CC;
#pragma unroll
    for (int c = 0; c < K1_CC; ++c) {
      float xv[12];
      const float4 a0 = *reinterpret_cast<const float4*>(&xs[buf][c][4 * t]);
      const float4 a1 = *reinterpret_cast<const float4*>(&xs[buf][c][4 * t + 4]);
      const float4 a2 = *reinterpret_cast<const float4*>(&xs[buf][c][4 * t + 8]);
      xv[0] = a0.x; xv[1] = a0.y; xv[2]  = a0.z; xv[3]  = a0.w;
      xv[4] = a1.x; xv[5] = a1.y; xv[6]  = a1.z; xv[7]  = a1.w;
      xv[8] = a2.x; xv[9] = a2.y; xv[10] = a2.z; xv[11] = a2.w;
      const float* Wc = W + (size_t)(c0 + c) * WIN; // wave-uniform address
#pragma unroll
      for (int h = 0; h < H_LEN; ++h) {
        const float* Wh = Wc + (size_t)h * (C_LEN * WIN);
#pragma unroll
        for (int w = 0; w < WIN; ++w) {
          const float wv = Wh[w]; // uniform -> SGPR
#pragma unroll
          for (int j = 0; j < 4; ++j)
            acc[h][j] = fmaf(xv[w + j], wv, acc[h][j]);
        }
      }
    }
    __syncthreads(); // drains prefetch vmcnt + halo lgkm, then barrier
    buf ^= 1;
  }

  float* dst = part + ((size_t)blockIdx.z * B_LEN * H_LEN + (size_t)b * H_LEN) * L_LEN
             + l0 + 4 * t;
#pragma unroll
  for (int h = 0; h < H_LEN; ++h) {
    float4 v;
    v.x = acc[h][0]; v.y = acc[h][1]; v.z = acc[h][2]; v.w = acc[h][3];
    *reinterpret_cast<float4*>(dst + (size_t)h * L_LEN) = v;
  }
}

// ---------------- Kernel 2: sum partials + softmax over L ----------------
__global__ __launch_bounds__(256) void softmax_rows(
    const float* __restrict__ part, float* __restrict__ focus, int nsplit)
{
  __shared__ float red[256];
  const int r = blockIdx.x; // b*H + h
  const int t = threadIdx.x;
  const size_t PART = (size_t)B_LEN * H_LEN * L_LEN;
  float v[16];
#pragma unroll
  for (int k = 0; k < 4; ++k) {
    const int i4 = (t + 256 * k) * 4;
    float4 a = *reinterpret_cast<const float4*>(&part[(size_t)r * L_LEN + i4]);
    v[4 * k + 0] = a.x; v[4 * k + 1] = a.y; v[4 * k + 2] = a.z; v[4 * k + 3] = a.w;
  }
  for (int s = 1; s < nsplit; ++s) {
#pragma unroll
    for (int k = 0; k < 4; ++k) {
      const int i4 = (t + 256 * k) * 4;
      float4 a = *reinterpret_cast<const float4*>(&part[(size_t)s * PART + (size_t)r * L_LEN + i4]);
      v[4 * k + 0] += a.x; v[4 * k + 1] += a.y; v[4 * k + 2] += a.z; v[4 * k + 3] += a.w;
    }
  }
  // bias b[h] is constant along L -> softmax-invariant -> skipped
  float m = v[0];
#pragma unroll
  for (int k = 1; k < 16; ++k) m = fmaxf(m, v[k]);
  red[t] = m;
  __syncthreads();
  for (int s = 128; s > 0; s >>= 1) {
    if (t < s) red[t] = fmaxf(red[t], red[t + s]);
    __syncthreads();
  }
  m = red[0];
  __syncthreads();
  float sum = 0.f;
#pragma unroll
  for (int k = 0; k < 16; ++k) { v[k] = __expf(v[k] - m); sum += v[k]; }
  red[t] = sum;
  __syncthreads();
  for (int s = 128; s > 0; s >>= 1) {
    if (t < s) red[t] += red[t + s];
    __syncthreads();
  }
  const float inv = 1.f / red[0];
#pragma unroll
  for (int k = 0; k < 4; ++k) {
    const int i4 = (t + 256 * k) * 4;
    float4 a;
    a.x = v[4 * k + 0] * inv; a.y = v[4 * k + 1] * inv;
    a.z = v[4 * k + 2] * inv; a.w = v[4 * k + 3] * inv;
    *reinterpret_cast<float4*>(&focus[(size_t)r * L_LEN + i4]) = a;
  }
}

// ---------------- Kernel 3a: partial pooled over an L-split ----------------
// grid (C/64, B, K3_NS), block 256 -> 1024 blocks (4/CU, 16 waves/CU).
// LDS-transposed x tile [64c][68]; focus via wave-uniform scalar loads.
#define K3_ST 68
#define K3_NS 4

__global__ __launch_bounds__(256) void pool_partial(
    const float* __restrict__ x, const float* __restrict__ focus,
    float* __restrict__ pool2)
{
  __shared__ float xs[64 * K3_ST];
  const int t = threadIdx.x;
  const int cl = t & 63;
  const int p = t >> 6;                              // h-group 0..3 (wave-uniform)
  const int pu = __builtin_amdgcn_readfirstlane(p);  // force SGPR for focus addressing
  const int b = blockIdx.y;
  const int c0 = blockIdx.x * 64;
  const int lbeg = blockIdx.z * (L_LEN / K3_NS);
  const float* f0 = focus + ((size_t)b * H_LEN + pu) * L_LEN;
  const float* f1 = f0 + 4 * (size_t)L_LEN;
  const float* xb = x + (size_t)b * C_LEN * L_LEN;
  const int srow = t >> 4;
  const int scol = (t & 15) * 4;
  float acc0 = 0.f, acc1 = 0.f;

  for (int l0 = lbeg; l0 < lbeg + L_LEN / K3_NS; l0 += 64) {
    __syncthreads();
#pragma unroll
    for (int pass = 0; pass < 4; ++pass) {
      const int c = srow + pass * 16;
      float4 v = *reinterpret_cast<const float4*>(&xb[(size_t)(c0 + c) * L_LEN + l0 + scol]);
      *reinterpret_cast<float4*>(&xs[c * K3_ST + scol]) = v;
    }
    __syncthreads();
#pragma unroll
    for (int l4 = 0; l4 < 16; ++l4) {
      const float4 xv = *reinterpret_cast<const float4*>(&xs[cl * K3_ST + 4 * l4]);
      const int li = l0 + 4 * l4;
      acc0 = fmaf(xv.x, f0[li + 0], acc0);
      acc0 = fmaf(xv.y, f0[li + 1], acc0);
      acc0 = fmaf(xv.z, f0[li + 2], acc0);
      acc0 = fmaf(xv.w, f0[li + 3], acc0);
      acc1 = fmaf(xv.x, f1[li + 0], acc1);
      acc1 = fmaf(xv.y, f1[li + 1], acc1);
      acc1 = fmaf(xv.z, f1[li + 2], acc1);
      acc1 = fmaf(xv.w, f1[li + 3], acc1);
    }
  }
  // partial pooled, layout [ls][b][c][h]
  float* dst = pool2 + (((size_t)blockIdx.z * B_LEN + b) * C_LEN + c0 + cl) * H_LEN;
  dst[p] = acc0;
  dst[p + 4] = acc1;
}

// ---------------- Kernel 3b: sum L-splits, max over heads ----------------
__global__ __launch_bounds__(256) void pool_reduce(
    const float* __restrict__ pool2, float* __restrict__ out)
{
  const int i = blockIdx.x * 256 + threadIdx.x; // over B*C
  float s[H_LEN];
#pragma unroll
  for (int h = 0; h < H_LEN; ++h) s[h] = 0.f;
  for (int ls = 0; ls < K3_NS; ++ls) {
    const float* src = pool2 + ((size_t)ls * B_LEN * C_LEN + i) * H_LEN;
    float4 a = *reinterpret_cast<const float4*>(src);
    float4 b4 = *reinterpret_cast<const float4*>(src + 4);
    s[0] += a.x; s[1] += a.y; s[2] += a.z; s[3] += a.w;
    s[4] += b4.x; s[5] += b4.y; s[6] += b4.z; s[7] += b4.w;
  }
  float m = s[0];
#pragma unroll
  for (int h = 1; h < H_LEN; ++h) m = fmaxf(m, s[h]);
  out[i] = m;
}

extern "C" void kernel_launch(void* const* d_in, const int* in_sizes, int n_in,
                              void* d_out, int out_size, void* d_ws, size_t ws_size,
                              hipStream_t stream)
{
  const float* x = (const float*)d_in[0];
  const float* W = (const float*)d_in[1];
  // d_in[2] = bias: constant along L, softmax-invariant -> no effect on output.
  float* out = (float*)d_out;
  float* ws = (float*)d_ws;

  const size_t PART = (size_t)B_LEN * H_LEN * L_LEN;            // 1M floats
  const size_t POOL2N = (size_t)K3_NS * B_LEN * C_LEN * H_LEN;  // 512K floats
  int nsplit = 8;
  if (ws_size < ((8 + 1) * PART + POOL2N) * sizeof(float)) nsplit = 4;
  if (ws_size < ((4 + 1) * PART + POOL2N) * sizeof(float)) nsplit = 2;
  if (ws_size < ((2 + 1) * PART + POOL2N) * sizeof(float)) nsplit = 1;

  float* part = ws;
  float* focus = ws + (size_t)nsplit * PART;
  float* pool2 = focus + PART;
  const int cper = C_LEN / nsplit;

  hipLaunchKernelGGL(conv_partial, dim3(L_LEN / K1_LT, B_LEN, nsplit), dim3(256), 0,
                     stream, x, W, part, cper);
  hipLaunchKernelGGL(softmax_rows, dim3(B_LEN * H_LEN), dim3(256), 0,
                     stream, part, focus, nsplit);
  hipLaunchKernelGGL(pool_partial, dim3(C_LEN / 64, B_LEN, K3_NS), dim3(256), 0,
                     stream, x, focus, pool2);
  hipLaunchKernelGGL(pool_reduce, dim3((B_LEN * C_LEN) / 256), dim3(256), 0,
                     stream, pool2, out);
}